// Round 1
// 362.449 us; speedup vs baseline: 1.0069x; 1.0069x over previous
//
#include <hip/hip_runtime.h>
#include <cstdint>
#include <cstddef>

#define NGRAPHS 512

static inline size_t align_up(size_t x, size_t a){ return (x + a - 1) & ~(a - 1); }

// ---------------- bf16 helpers ----------------
__device__ __forceinline__ unsigned short f2bf(float f){
  unsigned int u = __float_as_uint(f);
  u += 0x7FFFu + ((u >> 16) & 1u);          // round-to-nearest-even
  return (unsigned short)(u >> 16);
}
__device__ __forceinline__ float bflo(unsigned int u){ return __uint_as_float(u << 16); }
__device__ __forceinline__ float bfhi(unsigned int u){ return __uint_as_float(u & 0xffff0000u); }
__device__ __forceinline__ unsigned int pack2(float a, float b){
  return (unsigned)f2bf(a) | ((unsigned)f2bf(b) << 16);
}

typedef __attribute__((ext_vector_type(8))) short bf16x8;
typedef __attribute__((ext_vector_type(4))) float f32x4;

// ================= deterministic radix partition (no global atomics) =================
// blocks >= NBLK handle independent prep work (weight transpose, sums zero, graph bounds)
__global__ __launch_bounds__(256) void k_partcount(const int* __restrict__ src, const int* __restrict__ dst,
                                                   int* __restrict__ cntS, int* __restrict__ cntD, int n_edges, int NBLK,
                                                   const float* __restrict__ W1, unsigned short* __restrict__ Wt1,
                                                   const float* __restrict__ W2, unsigned short* __restrict__ Wt2,
                                                   float* __restrict__ sums,
                                                   const int* __restrict__ gids, int* __restrict__ gb, int n_nodes){
  __shared__ int cs[256], cd[256];
  if (blockIdx.x >= NBLK){
    long long u = (long long)(blockIdx.x - NBLK) * 256 + threadIdx.x;
    if (u < 128 * 256){
      int k = (int)(u / 256), n = (int)(u % 256);
      Wt1[(size_t)n * 128 + k] = f2bf(W1[u]);
      return;
    }
    u -= 128 * 256;
    if (u < 256 * 64){
      int k = (int)(u / 64), n = (int)(u % 64);
      Wt2[(size_t)n * 256 + k] = f2bf(W2[u]);
      return;
    }
    u -= 256 * 64;
    if (u < (long long)NGRAPHS * 64){ sums[u] = 0.f; return; }
    u -= (long long)NGRAPHS * 64;
    if (u < n_nodes){
      int i = (int)u;
      int g  = gids[i];
      int gp = (i > 0) ? gids[i - 1] : -1;
      for (int q = gp + 1; q <= g; ++q) gb[q] = i;       // sorted ids: gb[q] = first idx with gids >= q
      if (i == n_nodes - 1)
        for (int q = g + 1; q <= NGRAPHS; ++q) gb[q] = n_nodes;
    }
    return;
  }
  int tid = threadIdx.x;
  cs[tid] = 0; cd[tid] = 0;
  __syncthreads();
  int e0 = blockIdx.x * 4096;
  int e1 = min(e0 + 4096, n_edges);
  for (int e = e0 + tid; e < e1; e += 256){
    atomicAdd(&cs[src[e] >> 9], 1);
    atomicAdd(&cd[dst[e] >> 9], 1);
  }
  __syncthreads();
  cntS[blockIdx.x * 256 + tid] = cs[tid];
  cntD[blockIdx.x * 256 + tid] = cd[tid];
}

__global__ __launch_bounds__(256) void k_colscan(int* __restrict__ cntS, int* __restrict__ cntD,
                                                 int* __restrict__ totS, int* __restrict__ totD,
                                                 int nblk, int NB){
  int col = blockIdx.x;
  int* cnt; int* tot; int k;
  if (col < NB){ cnt = cntS; tot = totS; k = col; }
  else         { cnt = cntD; tot = totD; k = col - NB; }
  __shared__ int tsum[256];
  int tid = threadIdx.x;
  int i0 = 2 * tid, i1 = 2 * tid + 1;
  int a = (i0 < nblk) ? cnt[i0 * 256 + k] : 0;
  int b = (i1 < nblk) ? cnt[i1 * 256 + k] : 0;
  int s = a + b;
  tsum[tid] = s;
  __syncthreads();
  for (int off = 1; off < 256; off <<= 1){
    int t = (tid >= off) ? tsum[tid - off] : 0;
    __syncthreads();
    tsum[tid] += t;
    __syncthreads();
  }
  int pre = tsum[tid] - s;
  if (i0 < nblk) cnt[i0 * 256 + k] = pre;
  if (i1 < nblk) cnt[i1 * 256 + k] = pre + a;
  if (tid == 255) tot[k] = tsum[255];
}

__global__ __launch_bounds__(256) void k_scatter_det(const int* __restrict__ src, const int* __restrict__ dst,
                                                     const int* __restrict__ cntS, const int* __restrict__ cntD,
                                                     const int* __restrict__ totS, const int* __restrict__ totD,
                                                     int* __restrict__ baseS, int* __restrict__ baseD,
                                                     int2* __restrict__ pairD, int* __restrict__ srcS,
                                                     int n_edges, int NB){
  __shared__ int s1[256], s2[256], curS[256], curD[256];
  int tid = threadIdx.x;
  int b = blockIdx.x;
  int v1 = (tid < NB) ? totS[tid] : 0;
  int v2 = (tid < NB) ? totD[tid] : 0;
  s1[tid] = v1; s2[tid] = v2;
  __syncthreads();
  for (int off = 1; off < 256; off <<= 1){
    int t1 = (tid >= off) ? s1[tid - off] : 0;
    int t2 = (tid >= off) ? s2[tid - off] : 0;
    __syncthreads();
    s1[tid] += t1; s2[tid] += t2;
    __syncthreads();
  }
  int bS = s1[tid] - v1, bD = s2[tid] - v2;
  if (b == 0 && tid < NB){ baseS[tid] = bS; baseD[tid] = bD; }
  curS[tid] = bS + cntS[b * 256 + tid];
  curD[tid] = bD + cntD[b * 256 + tid];
  __syncthreads();
  int e0 = b * 4096, e1 = min(e0 + 4096, n_edges);
  for (int e = e0 + tid; e < e1; e += 256){
    int s = src[e], d = dst[e];
    int pd = atomicAdd(&curD[d >> 9], 1);
    pairD[pd] = make_int2(s, d);
    int ps = atomicAdd(&curS[s >> 9], 1);
    srcS[ps] = s;
  }
}

// fused per-bucket: histograms -> offs (in-block scan) + din_s/dout_s + counting-sort csr fill
__global__ __launch_bounds__(256) void k_bucket_build(const int2* __restrict__ pairD, const int* __restrict__ baseD,
                                                      const int* __restrict__ srcS, const int* __restrict__ baseS,
                                                      int* __restrict__ offs, float* __restrict__ din_s,
                                                      float* __restrict__ dout_s, int* __restrict__ csr_src,
                                                      int NB, int n, int n_edges){
  __shared__ int cd[512], cs[512], cur[512];
  __shared__ int tsum[256];
  int b = blockIdx.x, node0 = b << 9, tid = threadIdx.x;
  int nn = min(512, n - node0);
  for (int i = tid; i < 512; i += 256){ cd[i] = 0; cs[i] = 0; }
  __syncthreads();
  int jd0 = baseD[b], jd1 = (b + 1 < NB) ? baseD[b + 1] : n_edges;
  for (int j = jd0 + tid; j < jd1; j += 256) atomicAdd(&cd[pairD[j].y - node0], 1);
  int js0 = baseS[b], js1 = (b + 1 < NB) ? baseS[b + 1] : n_edges;
  for (int j = js0 + tid; j < js1; j += 256) atomicAdd(&cs[srcS[j] - node0], 1);
  __syncthreads();
  int a0 = cd[2 * tid], a1 = cd[2 * tid + 1];
  int s = a0 + a1;
  tsum[tid] = s;
  __syncthreads();
  for (int off = 1; off < 256; off <<= 1){
    int t = (tid >= off) ? tsum[tid - off] : 0;
    __syncthreads();
    tsum[tid] += t;
    __syncthreads();
  }
  int pre = tsum[tid] - s + jd0;
  cur[2 * tid]     = pre;
  cur[2 * tid + 1] = pre + a0;
  __syncthreads();
  for (int i = tid; i < nn; i += 256){
    offs[node0 + i]   = cur[i];
    din_s[node0 + i]  = 1.0f / sqrtf((float)max(cd[i], 1));
    dout_s[node0 + i] = 1.0f / sqrtf((float)max(cs[i], 1));
  }
  if (b == NB - 1 && tid == 0) offs[n] = n_edges;
  __syncthreads();
  for (int j = jd0 + tid; j < jd1; j += 256){
    int2 e = pairD[j];
    int p = atomicAdd(&cur[e.y - node0], 1);
    csr_src[p] = e.x;
  }
}

// ---------------- x -> bf16 with dout^-1/2 prescale (runs AFTER bucket_build) ----------------
__global__ __launch_bounds__(256) void k_prep2(const float* __restrict__ x,
                                               const float* __restrict__ dout_s,
                                               unsigned int* __restrict__ xb, long long total4){
  long long t = (long long)blockIdx.x * 256 + threadIdx.x;
  if (t >= total4) return;
  float4 v = ((const float4*)x)[t];
  float s = dout_s[t >> 5];
  xb[t * 2 + 0] = pack2(v.x * s, v.y * s);
  xb[t * 2 + 1] = pack2(v.z * s, v.w * s);
}

// ---------------- SpMM layer1 on prescaled bf16 x: 2 nodes/wave, unroll-8 + index prefetch ----
__global__ __launch_bounds__(256) void k_spmm1(const unsigned int* __restrict__ xb,
    const int* __restrict__ offs, const int* __restrict__ csr_src,
    unsigned int* __restrict__ aggb, int n_nodes){
  int node = (blockIdx.x * blockDim.x + threadIdx.x) >> 5;
  int lane = threadIdx.x & 31;
  if (node >= n_nodes) return;
  int j0 = offs[node], j1 = offs[node + 1];
  const uint2* xp = (const uint2*)xb;
  float4 acc = make_float4(0.f, 0.f, 0.f, 0.f);
  int j = j0;
  int nfull = (j1 - j0) >> 3;
  if (nfull > 0){
    int idx[8];
#pragma unroll
    for (int u = 0; u < 8; ++u) idx[u] = csr_src[j + u];
    for (int b = 0; b < nfull; ++b){
      int nidx[8];
      if (b + 1 < nfull){
#pragma unroll
        for (int u = 0; u < 8; ++u) nidx[u] = csr_src[j + 8 + u];
      }
      uint2 v[8];
#pragma unroll
      for (int u = 0; u < 8; ++u) v[u] = xp[(size_t)idx[u] * 32 + lane];
#pragma unroll
      for (int u = 0; u < 8; ++u){
        acc.x += bflo(v[u].x); acc.y += bfhi(v[u].x);
        acc.z += bflo(v[u].y); acc.w += bfhi(v[u].y);
      }
      if (b + 1 < nfull){
#pragma unroll
        for (int u = 0; u < 8; ++u) idx[u] = nidx[u];
      }
      j += 8;
    }
  }
  for (; j < j1; ++j){
    uint2 v = xp[(size_t)csr_src[j] * 32 + lane];
    acc.x += bflo(v.x); acc.y += bfhi(v.x);
    acc.z += bflo(v.y); acc.w += bfhi(v.y);
  }
  uint2 pk;
  pk.x = pack2(acc.x, acc.y);
  pk.y = pack2(acc.z, acc.w);
  ((uint2*)aggb)[(size_t)node * 32 + lane] = pk;
}

// ---------------- layer-1 GEMM: A tile (128x128, full K) resident in LDS, n-loop in-block ----
// C[M x 256] = relu(din * (A @ Wt1^T) + b1) * dout, written bf16
__global__ __launch_bounds__(256) void k_gemm1(const unsigned short* __restrict__ A,
    const unsigned short* __restrict__ Bt, unsigned short* __restrict__ C,
    int M, const float* __restrict__ din, const float* __restrict__ dout,
    const float* __restrict__ bias){
  constexpr int LDA = 136;   // shorts; 272B row stride -> 2-way (free) bank aliasing on ds_read_b128
  __shared__ __align__(16) unsigned short As[128 * LDA];
  __shared__ __align__(16) unsigned short Bs[64 * LDA];
  int tid = threadIdx.x;
  int bm0 = blockIdx.x * 128;
  int wid = tid >> 6, lane = tid & 63;
  int wm = wid * 32;
  int quad = lane >> 4, l16 = lane & 15;

  uint4 areg[8];
#pragma unroll
  for (int it = 0; it < 8; ++it){
    int i = tid + it * 256;
    int m = i >> 4, c = i & 15;
    int gr = bm0 + m;
    areg[it] = (gr < M) ? *(const uint4*)(A + (size_t)gr * 128 + c * 8) : make_uint4(0u, 0u, 0u, 0u);
  }
  uint4 breg[4];
#pragma unroll
  for (int it = 0; it < 4; ++it){
    int i = tid + it * 256;
    int n = i >> 4, c = i & 15;
    breg[it] = *(const uint4*)(Bt + (size_t)n * 128 + c * 8);
  }
#pragma unroll
  for (int it = 0; it < 8; ++it){
    int i = tid + it * 256;
    int m = i >> 4, c = i & 15;
    *(uint4*)&As[m * LDA + c * 8] = areg[it];
  }
#pragma unroll
  for (int it = 0; it < 4; ++it){
    int i = tid + it * 256;
    int n = i >> 4, c = i & 15;
    *(uint4*)&Bs[n * LDA + c * 8] = breg[it];
  }
  // per-row epilogue scales (this thread owns rows wm + t*16 + quad*4 + r)
  float rsv[2][4], rs2v[2][4];
#pragma unroll
  for (int t = 0; t < 2; ++t)
#pragma unroll
    for (int r = 0; r < 4; ++r){
      int gr = bm0 + wm + t * 16 + quad * 4 + r;
      rsv[t][r]  = (gr < M) ? din[gr]  : 0.f;
      rs2v[t][r] = (gr < M) ? dout[gr] : 0.f;
    }
  __syncthreads();

  for (int nt = 0; nt < 4; ++nt){
    if (nt < 3){
#pragma unroll
      for (int it = 0; it < 4; ++it){
        int i = tid + it * 256;
        int n = i >> 4, c = i & 15;
        breg[it] = *(const uint4*)(Bt + (size_t)((nt + 1) * 64 + n) * 128 + c * 8);
      }
    }
    f32x4 acc[2][4];
#pragma unroll
    for (int t = 0; t < 2; ++t)
#pragma unroll
      for (int u = 0; u < 4; ++u) acc[t][u] = f32x4{0.f, 0.f, 0.f, 0.f};
#pragma unroll
    for (int ks = 0; ks < 4; ++ks){
      bf16x8 af[2], bfr[4];
#pragma unroll
      for (int t = 0; t < 2; ++t)
        af[t] = *(const bf16x8*)&As[(wm + t * 16 + l16) * LDA + ks * 32 + quad * 8];
#pragma unroll
      for (int u = 0; u < 4; ++u)
        bfr[u] = *(const bf16x8*)&Bs[(u * 16 + l16) * LDA + ks * 32 + quad * 8];
#pragma unroll
      for (int t = 0; t < 2; ++t)
#pragma unroll
        for (int u = 0; u < 4; ++u)
          acc[t][u] = __builtin_amdgcn_mfma_f32_16x16x32_bf16(af[t], bfr[u], acc[t][u], 0, 0, 0);
    }
    float bv[4];
#pragma unroll
    for (int u = 0; u < 4; ++u) bv[u] = bias[nt * 64 + u * 16 + l16];
#pragma unroll
    for (int t = 0; t < 2; ++t){
#pragma unroll
      for (int r = 0; r < 4; ++r){
        int gr = bm0 + wm + t * 16 + quad * 4 + r;
        if (gr < M){
#pragma unroll
          for (int u = 0; u < 4; ++u){
            float cv = fmaxf(fmaf(acc[t][u][r], rsv[t][r], bv[u]), 0.f) * rs2v[t][r];
            C[(size_t)gr * 256 + nt * 64 + u * 16 + l16] = f2bf(cv);
          }
        }
      }
    }
    if (nt < 3){
      __syncthreads();
#pragma unroll
      for (int it = 0; it < 4; ++it){
        int i = tid + it * 256;
        int n = i >> 4, c = i & 15;
        *(uint4*)&Bs[n * LDA + c * 8] = breg[it];
      }
      __syncthreads();
    }
  }
}

// ---------------- fused SpMM layer2 + per-graph mean-pool sums (h2 never materialized) ----
#define SCHUNK 4
__global__ __launch_bounds__(256) void k_spmm2_fused(const unsigned short* __restrict__ t2,
    const int* __restrict__ offs, const int* __restrict__ csr_src,
    const float* __restrict__ din_s, const float* __restrict__ b2,
    const int* __restrict__ gb, float* __restrict__ sums){
  __shared__ float bs[64];
  int tid = threadIdx.x;
  int g = blockIdx.x & (NGRAPHS - 1);
  int chunk = blockIdx.x >> 9;
  int hw = chunk * 8 + (tid >> 5);          // 0..31
  int lane = tid & 31;
  if (tid < 64) bs[tid] = 0.f;
  __syncthreads();
  int g0 = gb[g], g1 = gb[g + 1];
  const unsigned int* tp = (const unsigned int*)t2;
  float2 bb = ((const float2*)b2)[lane];
  float sx = 0.f, sy = 0.f;
  for (int node = g0 + hw; node < g1; node += 32){
    int j0 = offs[node], j1 = offs[node + 1];
    float ax = 0.f, ay = 0.f;
    int j = j0;
    int nfull = (j1 - j0) >> 3;
    if (nfull > 0){
      int idx[8];
#pragma unroll
      for (int u = 0; u < 8; ++u) idx[u] = csr_src[j + u];
      for (int b = 0; b < nfull; ++b){
        int nidx[8];
        if (b + 1 < nfull){
#pragma unroll
          for (int u = 0; u < 8; ++u) nidx[u] = csr_src[j + 8 + u];
        }
        unsigned int v[8];
#pragma unroll
        for (int u = 0; u < 8; ++u) v[u] = tp[(size_t)idx[u] * 32 + lane];
#pragma unroll
        for (int u = 0; u < 8; ++u){ ax += bflo(v[u]); ay += bfhi(v[u]); }
        if (b + 1 < nfull){
#pragma unroll
          for (int u = 0; u < 8; ++u) idx[u] = nidx[u];
        }
        j += 8;
      }
    }
    for (; j < j1; ++j){
      unsigned int v = tp[(size_t)csr_src[j] * 32 + lane];
      ax += bflo(v);
      ay += bfhi(v);
    }
    float ds = din_s[node];
    sx += fmaxf(fmaf(ax, ds, bb.x), 0.f);
    sy += fmaxf(fmaf(ay, ds, bb.y), 0.f);
  }
  atomicAdd(&bs[2 * lane], sx);
  atomicAdd(&bs[2 * lane + 1], sy);
  __syncthreads();
  if (tid < 64) atomicAdd(&sums[(size_t)g * 64 + tid], bs[tid]);
}

// ---------------- MFMA bf16 GEMM (layer 2): BK=32, double-buffered LDS, register-preload ----
template<bool C_BF16, bool EPI, bool EPI2>
__global__ __launch_bounds__(256) void gemm_mfma(
    const unsigned short* __restrict__ A, const unsigned short* __restrict__ Bt, void* __restrict__ Cp,
    int M, int N, int K,
    const float* __restrict__ rowScaleC, const float* __restrict__ rowScaleC2,
    const float* __restrict__ bias){
  constexpr int BM = 128, BN = 64, BK = 32, LDA = 40;
  __shared__ __align__(16) unsigned short As[2][BM * LDA];
  __shared__ __align__(16) unsigned short Bs[2][BN * LDA];
  int tid = threadIdx.x;
  int bm0 = blockIdx.x * BM;
  int bn0 = blockIdx.y * BN;
  int wid = tid >> 6, lane = tid & 63;
  int wm = (wid >> 1) * 64, wn = (wid & 1) * 32;
  int quad = lane >> 4, l16 = lane & 15;
  f32x4 acc[4][2];
#pragma unroll
  for (int t = 0; t < 4; ++t)
#pragma unroll
    for (int u = 0; u < 2; ++u) acc[t][u] = f32x4{0.f, 0.f, 0.f, 0.f};

  uint2 ar[4], br[2];
  auto preload = [&](int kk){
#pragma unroll
    for (int it = 0; it < 4; ++it){
      int i = tid + it * 256;
      int m = i >> 3, c = i & 7;
      int gr = bm0 + m;
      ar[it] = (gr < M) ? *(const uint2*)(A + (size_t)gr * K + kk + c * 4) : make_uint2(0u, 0u);
    }
#pragma unroll
    for (int it = 0; it < 2; ++it){
      int i = tid + it * 256;
      int n = i >> 3, c = i & 7;
      br[it] = *(const uint2*)(Bt + (size_t)(bn0 + n) * K + kk + c * 4);
    }
  };
  auto commit = [&](int buf){
#pragma unroll
    for (int it = 0; it < 4; ++it){
      int i = tid + it * 256;
      int m = i >> 3, c = i & 7;
      *(uint2*)&As[buf][m * LDA + c * 4] = ar[it];
    }
#pragma unroll
    for (int it = 0; it < 2; ++it){
      int i = tid + it * 256;
      int n = i >> 3, c = i & 7;
      *(uint2*)&Bs[buf][n * LDA + c * 4] = br[it];
    }
  };

  preload(0);
  commit(0);
  __syncthreads();
  int nk = K / BK;
  for (int kb = 0; kb < nk; ++kb){
    int cur = kb & 1;
    if (kb + 1 < nk) preload((kb + 1) * BK);
    bf16x8 af[4], bfr[2];
#pragma unroll
    for (int t = 0; t < 4; ++t)
      af[t] = *(const bf16x8*)&As[cur][(wm + t * 16 + l16) * LDA + quad * 8];
#pragma unroll
    for (int u = 0; u < 2; ++u)
      bfr[u] = *(const bf16x8*)&Bs[cur][(wn + u * 16 + l16) * LDA + quad * 8];
#pragma unroll
    for (int t = 0; t < 4; ++t)
#pragma unroll
      for (int u = 0; u < 2; ++u)
        acc[t][u] = __builtin_amdgcn_mfma_f32_16x16x32_bf16(af[t], bfr[u], acc[t][u], 0, 0, 0);
    if (kb + 1 < nk){
      commit(cur ^ 1);
      __syncthreads();
    }
  }
  float bv[2] = {0.f, 0.f};
  if constexpr (EPI){ bv[0] = bias[bn0 + wn + l16]; bv[1] = bias[bn0 + wn + 16 + l16]; }
#pragma unroll
  for (int t = 0; t < 4; ++t){
#pragma unroll
    for (int r = 0; r < 4; ++r){
      int gr = bm0 + wm + t * 16 + quad * 4 + r;
      if (gr < M){
        float rs = 1.f, rs2 = 1.f;
        if constexpr (EPI)  rs  = rowScaleC[gr];
        if constexpr (EPI2) rs2 = rowScaleC2[gr];
#pragma unroll
        for (int u = 0; u < 2; ++u){
          int gc = bn0 + wn + u * 16 + l16;
          float cv = acc[t][u][r];
          if constexpr (EPI)  cv = fmaxf(fmaf(cv, rs, bv[u]), 0.f);
          if constexpr (EPI2) cv *= rs2;
          if constexpr (C_BF16) ((unsigned short*)Cp)[(size_t)gr * N + gc] = f2bf(cv);
          else                  ((float*)Cp)[(size_t)gr * N + gc] = cv;
        }
      }
    }
  }
}

// ---------------- classifier (counts from gb) ----------------
__global__ __launch_bounds__(256) void k_classifier(const float* __restrict__ sums, const int* __restrict__ gb,
    const float* __restrict__ Wc1, const float* __restrict__ bc1,
    const float* __restrict__ Wc2, const float* __restrict__ bc2,
    const float* __restrict__ Wc3, const float* __restrict__ bc3,
    const float* __restrict__ Wc4, const float* __restrict__ bc4,
    float* __restrict__ out){
  __shared__ float w1[64 * 18], w2[18 * 12], w3[12 * 6], w4[6 * 2];
  __shared__ float B1[18], B2[12], B3[6], B4[2];
  int tid = threadIdx.x;
  for (int i = tid; i < 64 * 18; i += 256) w1[i] = Wc1[i];
  for (int i = tid; i < 18 * 12; i += 256) w2[i] = Wc2[i];
  for (int i = tid; i < 12 * 6;  i += 256) w3[i] = Wc3[i];
  for (int i = tid; i < 6 * 2;   i += 256) w4[i] = Wc4[i];
  if (tid < 18) B1[tid] = bc1[tid];
  if (tid < 12) B2[tid] = bc2[tid];
  if (tid < 6)  B3[tid] = bc3[tid];
  if (tid < 2)  B4[tid] = bc4[tid];
  __syncthreads();
  int g = blockIdx.x * 256 + tid;
  float cnt = fmaxf((float)(gb[g + 1] - gb[g]), 1.0f);
  float h[64];
#pragma unroll
  for (int f = 0; f < 64; ++f) h[f] = sums[(size_t)g * 64 + f] / cnt;
  float t1[18];
#pragma unroll
  for (int j = 0; j < 18; ++j){
    float s = B1[j];
    for (int f = 0; f < 64; ++f) s = fmaf(h[f], w1[f * 18 + j], s);
    t1[j] = s;
  }
  float t2[12];
#pragma unroll
  for (int j = 0; j < 12; ++j){
    float s = B2[j];
    for (int f = 0; f < 18; ++f) s = fmaf(t1[f], w2[f * 12 + j], s);
    t2[j] = s;
  }
  float t3[6];
#pragma unroll
  for (int j = 0; j < 6; ++j){
    float s = B3[j];
    for (int f = 0; f < 12; ++f) s = fmaf(t2[f], w3[f * 6 + j], s);
    t3[j] = s;
  }
#pragma unroll
  for (int j = 0; j < 2; ++j){
    float s = B4[j];
    for (int f = 0; f < 6; ++f) s = fmaf(t3[f], w4[f * 2 + j], s);
    out[(size_t)g * 2 + j] = s;
  }
}

extern "C" void kernel_launch(void* const* d_in, const int* in_sizes, int n_in,
                              void* d_out, int out_size, void* d_ws, size_t ws_size,
                              hipStream_t stream){
  const float* x   = (const float*)d_in[0];
  const int*   src = (const int*)d_in[1];
  const int*   dst = (const int*)d_in[2];
  const int*   gid = (const int*)d_in[3];
  const float* W1  = (const float*)d_in[4];
  const float* b1  = (const float*)d_in[5];
  const float* W2  = (const float*)d_in[6];
  const float* b2  = (const float*)d_in[7];
  const float* Wc1 = (const float*)d_in[8];
  const float* bc1 = (const float*)d_in[9];
  const float* Wc2 = (const float*)d_in[10];
  const float* bc2 = (const float*)d_in[11];
  const float* Wc3 = (const float*)d_in[12];
  const float* bc3 = (const float*)d_in[13];
  const float* Wc4 = (const float*)d_in[14];
  const float* bc4 = (const float*)d_in[15];
  float* out = (float*)d_out;

  const int n_nodes = in_sizes[3];
  const int n_edges = in_sizes[1];
  const int F1 = 256, F2 = 64;
  const int NB   = (n_nodes + 511) >> 9;
  const int NBLK = (n_edges + 4095) / 4096;

  char* w = (char*)d_ws;
  size_t o = 0;
  auto alloc = [&](size_t bytes) -> char* {
    char* p = w + o;
    o = align_up(o + bytes, 256);
    return p;
  };
  float* sums      = (float*)alloc((size_t)NGRAPHS * F2 * 4);
  int*   gb        = (int*)  alloc((size_t)(NGRAPHS + 1) * 4);
  int*   cntS      = (int*)  alloc((size_t)NBLK * 256 * 4);
  int*   cntD      = (int*)  alloc((size_t)NBLK * 256 * 4);
  int*   totS      = (int*)  alloc((size_t)256 * 4);
  int*   totD      = (int*)  alloc((size_t)256 * 4);
  int*   baseS     = (int*)  alloc((size_t)256 * 4);
  int*   baseD     = (int*)  alloc((size_t)256 * 4);
  float* dout_s    = (float*)alloc((size_t)n_nodes * 4);
  float* din_s     = (float*)alloc((size_t)n_nodes * 4);
  int*   offs      = (int*)  alloc((size_t)(n_nodes + 1) * 4);
  int*   csr_src   = (int*)  alloc((size_t)n_edges * 4);
  unsigned short* Wt1 = (unsigned short*)alloc((size_t)256 * 128 * 2);
  unsigned short* Wt2 = (unsigned short*)alloc((size_t)64 * 256 * 2);
  unsigned int*   xb  = (unsigned int*)  alloc((size_t)n_nodes * 128 * 2);
  unsigned short* aggb= (unsigned short*)alloc((size_t)n_nodes * 128 * 2);
  unsigned short* h1b = (unsigned short*)alloc((size_t)n_nodes * F1 * 2);
  // aliases inside aggb region (consumed before spmm1 writes aggb)
  int2*  pairD = (int2*)aggb;
  int*   srcS  = (int*)((char*)aggb + (size_t)n_edges * 8);
  unsigned short* t2b = aggb;

  // deterministic radix partition + fused CSR build; misc prep work rides on partcount's grid
  {
    long long miscTotal = 128 * 256 + 256 * 64 + (long long)NGRAPHS * 64 + n_nodes;
    int miscBlocks = (int)((miscTotal + 255) / 256);
    k_partcount<<<NBLK + miscBlocks, 256, 0, stream>>>(src, dst, cntS, cntD, n_edges, NBLK,
                                                       W1, Wt1, W2, Wt2, sums, gid, gb, n_nodes);
  }
  k_colscan     <<<2 * NB, 256, 0, stream>>>(cntS, cntD, totS, totD, NBLK, NB);
  k_scatter_det <<<NBLK, 256, 0, stream>>>(src, dst, cntS, cntD, totS, totD, baseS, baseD, pairD, srcS, n_edges, NB);
  k_bucket_build<<<NB, 256, 0, stream>>>(pairD, baseD, srcS, baseS, offs, din_s, dout_s, csr_src, NB, n_nodes, n_edges);

  // x -> bf16 prescaled by dout^-1/2 (needs dout_s from bucket_build)
  {
    long long total4 = (long long)n_nodes * 32;
    k_prep2<<<(int)((total4 + 255) / 256), 256, 0, stream>>>(x, dout_s, xb, total4);
  }

  int gx = (n_nodes + 127) / 128;
  // layer 1
  {
    long long threads = (long long)n_nodes * 32;
    k_spmm1<<<(int)((threads + 255) / 256), 256, 0, stream>>>(xb, offs, csr_src, (unsigned int*)aggb, n_nodes);
    k_gemm1<<<gx, 256, 0, stream>>>(aggb, Wt1, h1b, n_nodes, din_s, dout_s, b1);
  }
  // layer 2: t2 = h1b @ W2; fused spmm2+pool accumulates graph sums directly
  {
    gemm_mfma<true, false, false><<<dim3(gx, 1), 256, 0, stream>>>(
        h1b, Wt2, t2b, n_nodes, F2, F1, nullptr, nullptr, nullptr);
    k_spmm2_fused<<<NGRAPHS * SCHUNK, 256, 0, stream>>>(t2b, offs, csr_src, din_s, b2, gb, sums);
  }
  // classifier
  k_classifier<<<NGRAPHS / 256, 256, 0, stream>>>(sums, gb, Wc1, bc1, Wc2, bc2, Wc3, bc3, Wc4, bc4, out);
}